// Round 3
// baseline (391.490 us; speedup 1.0000x reference)
//
#include <hip/hip_runtime.h>

#define VQ_D 64
#define VQ_K 512

typedef float f32x4 __attribute__((ext_vector_type(4)));

// ---------------------------------------------------------------------------
// numpy pairwise_sum replication for n=64 (global-memory input; used for s2).
// 8 accumulators r[j] = x2[j] + x2[j+8] + ... + x2[j+56] (sequential), then
// ((r0+r1)+(r2+r3)) + ((r4+r5)+(r6+r7)); squares rounded before summing.
// ---------------------------------------------------------------------------
__device__ __forceinline__ float np_sumsq64_g(const float* __restrict__ x)
{
    float r[8];
#pragma unroll
    for (int j = 0; j < 8; ++j) r[j] = __fmul_rn(x[j], x[j]);
#pragma unroll
    for (int i = 8; i < 64; i += 8) {
#pragma unroll
        for (int j = 0; j < 8; ++j)
            r[j] = __fadd_rn(r[j], __fmul_rn(x[i + j], x[i + j]));
    }
    return __fadd_rn(
        __fadd_rn(__fadd_rn(r[0], r[1]), __fadd_rn(r[2], r[3])),
        __fadd_rn(__fadd_rn(r[4], r[5]), __fadd_rn(r[6], r[7])));
}

// ---------------------------------------------------------------------------
// Pass A: bit-exact numpy-f32 replication (verified absmax 0.0 in R2):
//   dist[r,k] = fl( fl( s1[r] - fl(2*M[r,k]) ) + s2[k] ),
//   M = sequential-FMA dot (d ascending), argmin = first strict min.
// R3 restructure: z row held in 16 f32x4 ext-vectors, ALL constant-indexed
// (VGPR_Count must come back >~100 — R2's 60 VGPRs proved the compiler
// rematerialized z loads inside the k-loop -> VMEM-bound). Codebook reads
// are explicit float4 loads; s2 read as f32x4 from LDS.
// ---------------------------------------------------------------------------
__global__ __launch_bounds__(256) void vq_main_kernel(
    const float* __restrict__ z,
    const float* __restrict__ emb,
    float* __restrict__ zq_out,
    float* __restrict__ idx_out,
    double* __restrict__ partials,
    int rows, int use_atomic)
{
    __shared__ float s2[VQ_K];
    __shared__ double wsum[4];

    for (int k = threadIdx.x; k < VQ_K; k += 256)
        s2[k] = np_sumsq64_g(emb + (size_t)k * VQ_D);
    __syncthreads();

    const int row = blockIdx.x * 256 + threadIdx.x;
    double lsum = 0.0;

    if (row < rows) {
        // z row -> 16 f32x4 registers (constant indices only; no pointer to
        // this array ever escapes, so SROA keeps it in VGPRs).
        f32x4 zr[16];
        {
            const f32x4* zp = reinterpret_cast<const f32x4*>(z + (size_t)row * VQ_D);
#pragma unroll
            for (int q = 0; q < 16; ++q) zr[q] = zp[q];
        }

        // s1 = np.sum(z**2) with numpy pairwise order (element m at
        // zr[m>>2][m&3]; squares rounded before summing).
        float s1;
        {
            float r[8];
#pragma unroll
            for (int j = 0; j < 8; ++j) {
                const float x = zr[j >> 2][j & 3];
                r[j] = __fmul_rn(x, x);
            }
#pragma unroll
            for (int i = 1; i < 8; ++i) {
#pragma unroll
                for (int j = 0; j < 8; ++j) {
                    const int m = i * 8 + j;
                    const float x = zr[m >> 2][m & 3];
                    r[j] = __fadd_rn(r[j], __fmul_rn(x, x));
                }
            }
            s1 = __fadd_rn(
                __fadd_rn(__fadd_rn(r[0], r[1]), __fadd_rn(r[2], r[3])),
                __fadd_rn(__fadd_rn(r[4], r[5]), __fadd_rn(r[6], r[7])));
        }

        float best = 3.4e38f;
        int bi = 0;
        for (int k = 0; k < VQ_K; k += 4) {
            const f32x4* e0 = reinterpret_cast<const f32x4*>(emb + (size_t)(k + 0) * VQ_D);
            const f32x4* e1 = reinterpret_cast<const f32x4*>(emb + (size_t)(k + 1) * VQ_D);
            const f32x4* e2 = reinterpret_cast<const f32x4*>(emb + (size_t)(k + 2) * VQ_D);
            const f32x4* e3 = reinterpret_cast<const f32x4*>(emb + (size_t)(k + 3) * VQ_D);
            float a0 = 0.f, a1 = 0.f, a2 = 0.f, a3 = 0.f;
#pragma unroll
            for (int q = 0; q < 16; ++q) {
                const f32x4 v0 = e0[q];
                const f32x4 v1 = e1[q];
                const f32x4 v2 = e2[q];
                const f32x4 v3 = e3[q];
                const f32x4 zz = zr[q];
                // 4 independent sequential-FMA chains, d ascending per chain
                // (bit-exact BLAS k-order), interleaved for ILP.
                a0 = fmaf(zz.x, v0.x, a0);
                a1 = fmaf(zz.x, v1.x, a1);
                a2 = fmaf(zz.x, v2.x, a2);
                a3 = fmaf(zz.x, v3.x, a3);
                a0 = fmaf(zz.y, v0.y, a0);
                a1 = fmaf(zz.y, v1.y, a1);
                a2 = fmaf(zz.y, v2.y, a2);
                a3 = fmaf(zz.y, v3.y, a3);
                a0 = fmaf(zz.z, v0.z, a0);
                a1 = fmaf(zz.z, v1.z, a1);
                a2 = fmaf(zz.z, v2.z, a2);
                a3 = fmaf(zz.z, v3.z, a3);
                a0 = fmaf(zz.w, v0.w, a0);
                a1 = fmaf(zz.w, v1.w, a1);
                a2 = fmaf(zz.w, v2.w, a2);
                a3 = fmaf(zz.w, v3.w, a3);
            }
            const f32x4 s2v = *reinterpret_cast<const f32x4*>(&s2[k]);
            float t;
            t = __fadd_rn(__fsub_rn(s1, __fmul_rn(2.0f, a0)), s2v.x);
            if (t < best) { best = t; bi = k + 0; }
            t = __fadd_rn(__fsub_rn(s1, __fmul_rn(2.0f, a1)), s2v.y);
            if (t < best) { best = t; bi = k + 1; }
            t = __fadd_rn(__fsub_rn(s1, __fmul_rn(2.0f, a2)), s2v.z);
            if (t < best) { best = t; bi = k + 2; }
            t = __fadd_rn(__fsub_rn(s1, __fmul_rn(2.0f, a3)), s2v.w);
            if (t < best) { best = t; bi = k + 3; }
        }

        // z_q = fl(z + fl(e - z)) (STE rounding), f64 loss partial over
        // f32-rounded squared diffs. Identical ops to the verified R2 code.
        const f32x4* eb = reinterpret_cast<const f32x4*>(emb + (size_t)bi * VQ_D);
        f32x4* zq = reinterpret_cast<f32x4*>(zq_out + (size_t)row * VQ_D);
#pragma unroll
        for (int q = 0; q < 16; ++q) {
            const f32x4 ev = eb[q];
            const f32x4 zz = zr[q];
            f32x4 ov;
            const float d0 = __fsub_rn(ev.x, zz.x);
            const float d1 = __fsub_rn(ev.y, zz.y);
            const float d2 = __fsub_rn(ev.z, zz.z);
            const float d3 = __fsub_rn(ev.w, zz.w);
            ov.x = __fadd_rn(zz.x, d0);
            ov.y = __fadd_rn(zz.y, d1);
            ov.z = __fadd_rn(zz.z, d2);
            ov.w = __fadd_rn(zz.w, d3);
            zq[q] = ov;
            lsum += (double)__fmul_rn(d0, d0) + (double)__fmul_rn(d1, d1)
                  + (double)__fmul_rn(d2, d2) + (double)__fmul_rn(d3, d3);
        }
        idx_out[row] = (float)bi;
    }

    // Deterministic block reduction of the f64 loss partial.
#pragma unroll
    for (int off = 32; off > 0; off >>= 1)
        lsum += __shfl_down(lsum, off, 64);
    const int lane = threadIdx.x & 63, wid = threadIdx.x >> 6;
    if (lane == 0) wsum[wid] = lsum;
    __syncthreads();
    if (threadIdx.x == 0) {
        const double bs = wsum[0] + wsum[1] + wsum[2] + wsum[3];
        if (use_atomic) atomicAdd(partials, bs);
        else partials[blockIdx.x] = bs;
    }
}

// ---------------------------------------------------------------------------
// Pass B: deterministic reduce of per-block partials; write scalar loss.
// loss = (1 + BETA) * sum((z_q - z)^2) / N   with BETA = 0.25.
// ---------------------------------------------------------------------------
__global__ __launch_bounds__(256) void vq_finalize_kernel(
    const double* __restrict__ partials, int nparts,
    float* __restrict__ loss_out, double inv_n)
{
    __shared__ double wsum[4];
    double s = 0.0;
    for (int i = threadIdx.x; i < nparts; i += 256) s += partials[i];
#pragma unroll
    for (int off = 32; off > 0; off >>= 1)
        s += __shfl_down(s, off, 64);
    const int lane = threadIdx.x & 63, wid = threadIdx.x >> 6;
    if (lane == 0) wsum[wid] = s;
    __syncthreads();
    if (threadIdx.x == 0)
        loss_out[0] = (float)(1.25 * (wsum[0] + wsum[1] + wsum[2] + wsum[3]) * inv_n);
}

extern "C" void kernel_launch(void* const* d_in, const int* in_sizes, int n_in,
                              void* d_out, int out_size, void* d_ws, size_t ws_size,
                              hipStream_t stream) {
    const float* z   = (const float*)d_in[0];
    const float* emb = (const float*)d_in[1];
    float* out = (float*)d_out;

    const int zn   = in_sizes[0];      // 64*4096*64 = 16777216
    const int rows = zn / VQ_D;        // 262144

    // Output layout (f32 buffer, tuple flattened in return order):
    // [0, zn) z_q | [zn] loss | [zn+1, zn+1+rows) indices (as floats)
    float* zq_out   = out;
    float* loss_out = out + zn;
    float* idx_out  = out + zn + 1;

    const int grid = (rows + 255) / 256;   // 1024 blocks
    double* partials = (double*)d_ws;
    const int use_atomic = (ws_size < (size_t)grid * sizeof(double)) ? 1 : 0;
    if (use_atomic) {
        hipMemsetAsync(d_ws, 0, sizeof(double), stream);
    }

    vq_main_kernel<<<grid, 256, 0, stream>>>(z, emb, zq_out, idx_out,
                                             partials, rows, use_atomic);
    vq_finalize_kernel<<<1, 256, 0, stream>>>(partials, use_atomic ? 1 : grid,
                                              loss_out, 1.0 / (double)zn);
}

// Round 5
// 356.300 us; speedup vs baseline: 1.0988x; 1.0988x over previous
//
#include <hip/hip_runtime.h>

#define VQ_D 64
#define VQ_K 512
#define W_FLAG 2.0e-4f

typedef float f32x4 __attribute__((ext_vector_type(4)));
typedef short bf16x8 __attribute__((ext_vector_type(8)));

// f32 -> bf16 RNE (no NaN inputs here)
__device__ __forceinline__ unsigned short f2bf(float f) {
    unsigned u = __float_as_uint(f);
    unsigned r = u + 0x7FFFu + ((u >> 16) & 1u);
    return (unsigned short)(r >> 16);
}
__device__ __forceinline__ float bf2f(unsigned short h) {
    return __uint_as_float(((unsigned)h) << 16);
}

// Monotone float -> unsigned map (total order preserved, negatives below
// positives). R4 bug: raw IEEE bits compared unsigned put negative t's
// ABOVE positives -> argmin picked the smallest positive t on every row.
__device__ __forceinline__ unsigned ordkey(float f) {
    const unsigned u = __float_as_uint(f);
    return u ^ (unsigned)(((int)u >> 31) | (int)0x80000000);
}
__device__ __forceinline__ float ordkey_inv(unsigned k) {
    const unsigned u = (k & 0x80000000u) ? (k ^ 0x80000000u) : ~k;
    return __uint_as_float(u);
}

// ---------------------------------------------------------------------------
// numpy pairwise_sum replication for n=64 (proven bit-exact in R2).
// ---------------------------------------------------------------------------
__device__ __forceinline__ float np_sumsq64_g(const float* __restrict__ x)
{
    float r[8];
#pragma unroll
    for (int j = 0; j < 8; ++j) r[j] = __fmul_rn(x[j], x[j]);
#pragma unroll
    for (int i = 8; i < 64; i += 8) {
#pragma unroll
        for (int j = 0; j < 8; ++j)
            r[j] = __fadd_rn(r[j], __fmul_rn(x[i + j], x[i + j]));
    }
    return __fadd_rn(
        __fadd_rn(__fadd_rn(r[0], r[1]), __fadd_rn(r[2], r[3])),
        __fadd_rn(__fadd_rn(r[4], r[5]), __fadd_rn(r[6], r[7])));
}

// ---------------------------------------------------------------------------
// K0: prep — per code: exact s2 (numpy order) + bf16 hi/lo split of emb.
// ---------------------------------------------------------------------------
__global__ __launch_bounds__(256) void vq_prep(
    const float* __restrict__ emb,
    unsigned short* __restrict__ ebh,
    unsigned short* __restrict__ ebl,
    float* __restrict__ s2g)
{
    const int c = blockIdx.x * 256 + threadIdx.x;
    if (c >= VQ_K) return;
    const float* e = emb + (size_t)c * VQ_D;
    s2g[c] = np_sumsq64_g(e);
#pragma unroll 8
    for (int d = 0; d < VQ_D; ++d) {
        const float f = e[d];
        const unsigned short h = f2bf(f);
        ebh[c * VQ_D + d] = h;
        ebl[c * VQ_D + d] = f2bf(__fsub_rn(f, bf2f(h)));
    }
}

// ---------------------------------------------------------------------------
// K1: MFMA approx scores (bf16 hi/lo split: hh + hl + lh) + per-row top-2 ->
// flag near-ties (gap <= W_FLAG) -> exact R2-numerics rescan for flagged
// rows -> fused z_q/STE/loss/idx outputs.
// Block: 512 threads = 8 waves; wave = 16 rows; block = 128 rows.
// Codebook streamed through LDS in 8 chunks of 64 codes (hi+lo, 16 KB).
// ---------------------------------------------------------------------------
__global__ __launch_bounds__(512) void vq_mfma_kernel(
    const float* __restrict__ z,
    const float* __restrict__ emb,
    const unsigned short* __restrict__ ebh,
    const unsigned short* __restrict__ ebl,
    const float* __restrict__ s2g,
    float* __restrict__ zq_out,
    float* __restrict__ idx_out,
    double* __restrict__ partials)
{
    __shared__ __align__(16) unsigned short cbuf[8192]; // hi 8KB | lo 8KB
    __shared__ float s2s[VQ_K];
    __shared__ int rowinfo[8 * 16];
    __shared__ double wsum[8];

    const int tid  = threadIdx.x;
    const int wid  = tid >> 6;
    const int lane = tid & 63;
    const int l15  = lane & 15;
    const int kg   = lane >> 4;            // k-group 0..3
    const int rowbase = blockIdx.x * 128 + wid * 16;

    for (int i = tid; i < VQ_K; i += 512) s2s[i] = s2g[i];

    // ---- A fragments: z rows -> bf16 hi/lo, held across all col-tiles ----
    // lane: row = l15, k = kc*32 + kg*8 + j. A and B use the SAME (hi,reg)
    // k-map, so any k-mapping misbelief cancels in the dot product.
    bf16x8 Ah[2], Al[2];
#pragma unroll
    for (int kc = 0; kc < 2; ++kc) {
        const float* zp = z + (size_t)(rowbase + l15) * VQ_D + kc * 32 + kg * 8;
        const f32x4 v0 = *reinterpret_cast<const f32x4*>(zp);
        const f32x4 v1 = *reinterpret_cast<const f32x4*>(zp + 4);
        bf16x8 ah, al;
#pragma unroll
        for (int j = 0; j < 8; ++j) {
            const float f = (j < 4) ? v0[j] : v1[j - 4];
            const unsigned short h = f2bf(f);
            ah[j] = (short)h;
            al[j] = (short)f2bf(__fsub_rn(f, bf2f(h)));
        }
        Ah[kc] = ah; Al[kc] = al;
    }

    unsigned long long m1[4], m2[4];
#pragma unroll
    for (int j = 0; j < 4; ++j) { m1[j] = ~0ull; m2[j] = ~0ull; }

    for (int ch = 0; ch < 8; ++ch) {
        __syncthreads();                    // prev chunk fully consumed
        {   // stage chunk: 512 threads x (16B hi + 16B lo), XOR-swizzled
            const int code = tid >> 3;      // 0..63 within chunk
            const int kseg = tid & 7;       // 8 segs of 8 bf16
            const int gcode = ch * 64 + code;
            const unsigned sw = ((unsigned)(code * 128 + kseg * 16))
                              ^ (unsigned)((code & 7) << 4);
            *reinterpret_cast<uint4*>((char*)cbuf + sw) =
                reinterpret_cast<const uint4*>(ebh)[gcode * 8 + kseg];
            *reinterpret_cast<uint4*>((char*)cbuf + 8192 + sw) =
                reinterpret_cast<const uint4*>(ebl)[gcode * 8 + kseg];
        }
        __syncthreads();

#pragma unroll
        for (int ct = 0; ct < 4; ++ct) {
            const int coderel = ct * 16 + l15;
            f32x4 acc = {0.f, 0.f, 0.f, 0.f};
#pragma unroll
            for (int kc = 0; kc < 2; ++kc) {
                const unsigned off = ((unsigned)(coderel * 128 + kc * 64 + kg * 16))
                                   ^ (unsigned)((coderel & 7) << 4);
                const bf16x8 Bh = *reinterpret_cast<const bf16x8*>((const char*)cbuf + off);
                const bf16x8 Bl = *reinterpret_cast<const bf16x8*>((const char*)cbuf + 8192 + off);
                acc = __builtin_amdgcn_mfma_f32_16x16x32_bf16(Ah[kc], Bh, acc, 0, 0, 0);
                acc = __builtin_amdgcn_mfma_f32_16x16x32_bf16(Ah[kc], Bl, acc, 0, 0, 0);
                acc = __builtin_amdgcn_mfma_f32_16x16x32_bf16(Al[kc], Bh, acc, 0, 0, 0);
            }
            const int codeg = ch * 64 + ct * 16 + l15;
            const float s2v = s2s[codeg];
#pragma unroll
            for (int j = 0; j < 4; ++j) {   // row = kg*4 + j (C/D: m89 layout)
                const float t = fmaf(-2.0f, acc[j], s2v);
                const unsigned long long key =
                    (((unsigned long long)ordkey(t)) << 32) | (unsigned)codeg;
                if (key < m1[j]) { m2[j] = m1[j]; m1[j] = key; }
                else if (key < m2[j]) { m2[j] = key; }
            }
        }
    }

    // ---- top-2 merge across the 16 lanes sharing each row group ----
#pragma unroll
    for (int m = 1; m <= 8; m <<= 1) {
#pragma unroll
        for (int j = 0; j < 4; ++j) {
            const unsigned long long o1 = __shfl_xor(m1[j], m, 64);
            const unsigned long long o2 = __shfl_xor(m2[j], m, 64);
            const unsigned long long lo_ = (m1[j] < o1) ? m1[j] : o1;
            const unsigned long long hi_ = (m1[j] < o1) ? o1 : m1[j];
            const unsigned long long s2m = (m2[j] < o2) ? m2[j] : o2;
            m1[j] = lo_;
            m2[j] = (hi_ < s2m) ? hi_ : s2m;
        }
    }
    if (l15 == 0) {
#pragma unroll
        for (int j = 0; j < 4; ++j) {
            const float t1 = ordkey_inv((unsigned)(m1[j] >> 32));
            const float t2 = ordkey_inv((unsigned)(m2[j] >> 32));
            const int idx = (int)(m1[j] & 0x1FFull);
            const int flag = (__fsub_rn(t2, t1) <= W_FLAG) ? 1 : 0;
            rowinfo[wid * 16 + kg * 4 + j] = idx | (flag << 16);
        }
    }

    // ---- slow path: exact (R2-numerics) rescan for flagged rows ----
    for (int r = 0; r < 16; ++r) {
        const int info = rowinfo[wid * 16 + r];   // wave-uniform broadcast
        if (!(info >> 16)) continue;
        const float* zrow = z + (size_t)(rowbase + r) * VQ_D;
        const float s1 = np_sumsq64_g(zrow);      // numpy pairwise, exact
        unsigned long long best = ~0ull;
#pragma unroll
        for (int i = 0; i < 8; ++i) {
            const int c = lane * 8 + i;
            const float* e = emb + (size_t)c * VQ_D;
            float a = 0.f;
#pragma unroll
            for (int d = 0; d < VQ_D; ++d)        // sequential BLAS k-order
                a = fmaf(zrow[d], e[d], a);
            const float t = __fadd_rn(__fsub_rn(s1, __fmul_rn(2.0f, a)), s2s[c]);
            // t ~ 64 > 0 always -> raw-bit order is fine here (proven R2).
            const unsigned long long key =
                (((unsigned long long)__float_as_uint(t)) << 32) | (unsigned)c;
            if (key < best) best = key;
        }
#pragma unroll
        for (int m = 1; m <= 32; m <<= 1) {
            const unsigned long long o = __shfl_xor(best, m, 64);
            best = (o < best) ? o : best;
        }
        if (lane == 0) rowinfo[wid * 16 + r] = (int)(best & 0x1FFull);
    }

    // ---- z_q / STE / loss (ops identical to verified R2) ----
    double lsum = 0.0;
    {
        const int r = lane >> 2, seg = lane & 3;  // 4 lanes per row, 64B each
        const int idx = rowinfo[wid * 16 + r] & 0x1FF;
        const float* zp = z + (size_t)(rowbase + r) * VQ_D + seg * 16;
        const float* ep = emb + (size_t)idx * VQ_D + seg * 16;
        float* qp = zq_out + (size_t)(rowbase + r) * VQ_D + seg * 16;
#pragma unroll
        for (int i = 0; i < 4; ++i) {
            const f32x4 zv = *reinterpret_cast<const f32x4*>(zp + i * 4);
            const f32x4 ev = *reinterpret_cast<const f32x4*>(ep + i * 4);
            f32x4 ov;
#pragma unroll
            for (int j = 0; j < 4; ++j) {
                const float d = __fsub_rn(ev[j], zv[j]);
                ov[j] = __fadd_rn(zv[j], d);
                lsum += (double)__fmul_rn(d, d);
            }
            *reinterpret_cast<f32x4*>(qp + i * 4) = ov;
        }
        if (lane < 16)
            idx_out[rowbase + lane] = (float)(rowinfo[wid * 16 + lane] & 0x1FF);
    }

    // ---- deterministic loss reduction ----
#pragma unroll
    for (int off = 32; off > 0; off >>= 1)
        lsum += __shfl_down(lsum, off, 64);
    if (lane == 0) wsum[wid] = lsum;
    __syncthreads();
    if (tid == 0) {
        double s = 0.0;
#pragma unroll
        for (int w = 0; w < 8; ++w) s += wsum[w];
        partials[blockIdx.x] = s;
    }
}

// ---------------------------------------------------------------------------
// Finalize: reduce partials -> loss = 1.25 * sum / N.
// ---------------------------------------------------------------------------
__global__ __launch_bounds__(256) void vq_finalize_kernel(
    const double* __restrict__ partials, int nparts,
    float* __restrict__ loss_out, double inv_n)
{
    __shared__ double ws[4];
    double s = 0.0;
    for (int i = threadIdx.x; i < nparts; i += 256) s += partials[i];
#pragma unroll
    for (int off = 32; off > 0; off >>= 1)
        s += __shfl_down(s, off, 64);
    const int lane = threadIdx.x & 63, w = threadIdx.x >> 6;
    if (lane == 0) ws[w] = s;
    __syncthreads();
    if (threadIdx.x == 0)
        loss_out[0] = (float)(1.25 * (ws[0] + ws[1] + ws[2] + ws[3]) * inv_n);
}

// ---------------------------------------------------------------------------
// Fallback (proven R2 kernel) if ws is too small for the MFMA path.
// ---------------------------------------------------------------------------
__global__ __launch_bounds__(256) void vq_main_kernel(
    const float* __restrict__ z, const float* __restrict__ emb,
    float* __restrict__ zq_out, float* __restrict__ idx_out,
    double* __restrict__ partials, int rows, int use_atomic)
{
    __shared__ float s2[VQ_K];
    __shared__ double wsb[4];
    for (int k = threadIdx.x; k < VQ_K; k += 256)
        s2[k] = np_sumsq64_g(emb + (size_t)k * VQ_D);
    __syncthreads();
    const int row = blockIdx.x * 256 + threadIdx.x;
    double lsum = 0.0;
    if (row < rows) {
        float zr[VQ_D];
        const float* zp = z + (size_t)row * VQ_D;
#pragma unroll
        for (int d = 0; d < VQ_D; d += 4) {
            const float4 v = *reinterpret_cast<const float4*>(zp + d);
            zr[d] = v.x; zr[d+1] = v.y; zr[d+2] = v.z; zr[d+3] = v.w;
        }
        const float s1 = np_sumsq64_g(zr);
        float best = 3.4e38f; int bi = 0;
        for (int k = 0; k < VQ_K; k += 4) {
            const float* e0 = emb + (size_t)(k+0) * VQ_D;
            const float* e1 = emb + (size_t)(k+1) * VQ_D;
            const float* e2 = emb + (size_t)(k+2) * VQ_D;
            const float* e3 = emb + (size_t)(k+3) * VQ_D;
            float a0=0.f,a1=0.f,a2=0.f,a3=0.f;
#pragma unroll
            for (int d = 0; d < VQ_D; ++d) {
                const float zd = zr[d];
                a0 = fmaf(zd, e0[d], a0); a1 = fmaf(zd, e1[d], a1);
                a2 = fmaf(zd, e2[d], a2); a3 = fmaf(zd, e3[d], a3);
            }
            float t;
            t = __fadd_rn(__fsub_rn(s1, __fmul_rn(2.0f, a0)), s2[k+0]);
            if (t < best) { best = t; bi = k+0; }
            t = __fadd_rn(__fsub_rn(s1, __fmul_rn(2.0f, a1)), s2[k+1]);
            if (t < best) { best = t; bi = k+1; }
            t = __fadd_rn(__fsub_rn(s1, __fmul_rn(2.0f, a2)), s2[k+2]);
            if (t < best) { best = t; bi = k+2; }
            t = __fadd_rn(__fsub_rn(s1, __fmul_rn(2.0f, a3)), s2[k+3]);
            if (t < best) { best = t; bi = k+3; }
        }
        const float* eb = emb + (size_t)bi * VQ_D;
        float* zq = zq_out + (size_t)row * VQ_D;
#pragma unroll
        for (int d = 0; d < VQ_D; d += 4) {
            float4 ev, ov;
            ev.x = eb[d]; ev.y = eb[d+1]; ev.z = eb[d+2]; ev.w = eb[d+3];
            const float d0 = __fsub_rn(ev.x, zr[d]);
            const float d1 = __fsub_rn(ev.y, zr[d+1]);
            const float d2 = __fsub_rn(ev.z, zr[d+2]);
            const float d3 = __fsub_rn(ev.w, zr[d+3]);
            ov.x = __fadd_rn(zr[d], d0);   ov.y = __fadd_rn(zr[d+1], d1);
            ov.z = __fadd_rn(zr[d+2], d2); ov.w = __fadd_rn(zr[d+3], d3);
            *reinterpret_cast<float4*>(zq + d) = ov;
            lsum += (double)__fmul_rn(d0,d0) + (double)__fmul_rn(d1,d1)
                  + (double)__fmul_rn(d2,d2) + (double)__fmul_rn(d3,d3);
        }
        idx_out[row] = (float)bi;
    }
#pragma unroll
    for (int off = 32; off > 0; off >>= 1)
        lsum += __shfl_down(lsum, off, 64);
    const int lane = threadIdx.x & 63, w = threadIdx.x >> 6;
    if (lane == 0) wsb[w] = lsum;
    __syncthreads();
    if (threadIdx.x == 0) {
        const double bs = wsb[0] + wsb[1] + wsb[2] + wsb[3];
        if (use_atomic) atomicAdd(partials, bs);
        else partials[blockIdx.x] = bs;
    }
}

extern "C" void kernel_launch(void* const* d_in, const int* in_sizes, int n_in,
                              void* d_out, int out_size, void* d_ws, size_t ws_size,
                              hipStream_t stream) {
    const float* z   = (const float*)d_in[0];
    const float* emb = (const float*)d_in[1];
    float* out = (float*)d_out;

    const int zn   = in_sizes[0];        // 16777216
    const int rows = zn / VQ_D;          // 262144

    float* zq_out   = out;
    float* loss_out = out + zn;
    float* idx_out  = out + zn + 1;

    // ws layout: [0) ebh 64KB | [64K) ebl 64KB | [128K) s2 2KB | [130K) partials
    const size_t OFF_EBL  = 65536, OFF_S2 = 131072, OFF_PART = 133120;
    const int nblocks = rows / 128;      // 2048
    const size_t need = OFF_PART + (size_t)nblocks * sizeof(double);

    if (ws_size >= need && (rows % 128) == 0) {
        unsigned short* ebh = (unsigned short*)d_ws;
        unsigned short* ebl = (unsigned short*)((char*)d_ws + OFF_EBL);
        float* s2g          = (float*)((char*)d_ws + OFF_S2);
        double* partials    = (double*)((char*)d_ws + OFF_PART);

        vq_prep<<<2, 256, 0, stream>>>(emb, ebh, ebl, s2g);
        vq_mfma_kernel<<<nblocks, 512, 0, stream>>>(
            z, emb, ebh, ebl, s2g, zq_out, idx_out, partials);
        vq_finalize_kernel<<<1, 256, 0, stream>>>(
            partials, nblocks, loss_out, 1.0 / (double)zn);
    } else {
        const int grid = (rows + 255) / 256;
        double* partials = (double*)d_ws;
        const int use_atomic = (ws_size < (size_t)grid * sizeof(double)) ? 1 : 0;
        if (use_atomic) hipMemsetAsync(d_ws, 0, sizeof(double), stream);
        vq_main_kernel<<<grid, 256, 0, stream>>>(z, emb, zq_out, idx_out,
                                                 partials, rows, use_atomic);
        vq_finalize_kernel<<<1, 256, 0, stream>>>(partials, use_atomic ? 1 : grid,
                                                  loss_out, 1.0 / (double)zn);
    }
}

// Round 6
// 286.230 us; speedup vs baseline: 1.3677x; 1.2448x over previous
//
#include <hip/hip_runtime.h>

#define VQ_D 64
#define VQ_K 512
#define W_FLAG 2.0e-4f

typedef float f32x4 __attribute__((ext_vector_type(4)));
typedef short bf16x8 __attribute__((ext_vector_type(8)));

// f32 -> bf16 RNE (no NaN inputs here)
__device__ __forceinline__ unsigned short f2bf(float f) {
    unsigned u = __float_as_uint(f);
    unsigned r = u + 0x7FFFu + ((u >> 16) & 1u);
    return (unsigned short)(r >> 16);
}
__device__ __forceinline__ float bf2f(unsigned short h) {
    return __uint_as_float(((unsigned)h) << 16);
}

// Monotone float->u32 (negatives below positives) — R4 lesson.
__device__ __forceinline__ unsigned ordkey(float f) {
    const unsigned u = __float_as_uint(f);
    return u ^ (unsigned)(((int)u >> 31) | (int)0x80000000);
}
__device__ __forceinline__ float ordkey_inv(unsigned k) {
    const unsigned u = (k & 0x80000000u) ? (k ^ 0x80000000u) : ~k;
    return __uint_as_float(u);
}

// ---------------------------------------------------------------------------
// numpy pairwise_sum replication for n=64 (proven bit-exact in R2).
// ---------------------------------------------------------------------------
__device__ __forceinline__ float np_sumsq64_g(const float* __restrict__ x)
{
    float r[8];
#pragma unroll
    for (int j = 0; j < 8; ++j) r[j] = __fmul_rn(x[j], x[j]);
#pragma unroll
    for (int i = 8; i < 64; i += 8) {
#pragma unroll
        for (int j = 0; j < 8; ++j)
            r[j] = __fadd_rn(r[j], __fmul_rn(x[i + j], x[i + j]));
    }
    return __fadd_rn(
        __fadd_rn(__fadd_rn(r[0], r[1]), __fadd_rn(r[2], r[3])),
        __fadd_rn(__fadd_rn(r[4], r[5]), __fadd_rn(r[6], r[7])));
}

// ---------------------------------------------------------------------------
// K0: prep. Grid 16x256 = 4096 threads = one per B-fragment lane-slot.
// Fragment-major layout: frag f = tile*2 + kc (tile = code>>4), lane L holds
// code = tile*16 + (L&15), k = kc*32 + (L>>4)*8 + j, j=0..7; flat bf16 offset
// (f*64+L)*8+j. Main kernel then loads B-operands as coalesced 16B/lane.
// Blocks 0-1 additionally compute exact s2 (numpy order) per code.
// ---------------------------------------------------------------------------
__global__ __launch_bounds__(256) void vq_prep(
    const float* __restrict__ emb,
    unsigned short* __restrict__ ebh,
    unsigned short* __restrict__ ebl,
    float* __restrict__ s2g)
{
    const int tg = blockIdx.x * 256 + threadIdx.x;   // 0..4095
    const int f  = tg >> 6;                          // fragment 0..63
    const int L  = tg & 63;                          // lane slot
    const int c  = (f >> 1) * 16 + (L & 15);         // code
    const int k0 = (f & 1) * 32 + (L >> 4) * 8;      // k base

    const float* e = emb + (size_t)c * VQ_D + k0;
    const f32x4 v0 = *reinterpret_cast<const f32x4*>(e);
    const f32x4 v1 = *reinterpret_cast<const f32x4*>(e + 4);
    bf16x8 h8, l8;
#pragma unroll
    for (int j = 0; j < 8; ++j) {
        const float fv = (j < 4) ? v0[j] : v1[j - 4];
        const unsigned short h = f2bf(fv);
        h8[j] = (short)h;
        l8[j] = (short)f2bf(__fsub_rn(fv, bf2f(h)));
    }
    reinterpret_cast<bf16x8*>(ebh)[f * 64 + L] = h8;
    reinterpret_cast<bf16x8*>(ebl)[f * 64 + L] = l8;

    if (blockIdx.x < 2) {
        const int c2 = blockIdx.x * 256 + threadIdx.x;   // 0..511
        s2g[c2] = np_sumsq64_g(emb + (size_t)c2 * VQ_D);
    }
}

// ---------------------------------------------------------------------------
// K1: barrier-free MFMA argmin. 512 thr = 8 waves; wave owns 16 rows.
// Per tile (16 codes): 4 coalesced global fragment loads + 6 MFMAs
// (hi/lo split: hh+hl+lh) + cheap float top-2 update. No LDS staging, no
// __syncthreads in the hot loop -> compiler pipelines, waves stay runnable.
// Near-ties (gap <= W_FLAG) resolved by the exact R2-numerics rescan.
// ---------------------------------------------------------------------------
__global__ __launch_bounds__(512) void vq_mfma_kernel(
    const float* __restrict__ z,
    const float* __restrict__ emb,
    const unsigned short* __restrict__ ebh,
    const unsigned short* __restrict__ ebl,
    const float* __restrict__ s2g,
    float* __restrict__ zq_out,
    float* __restrict__ idx_out,
    double* __restrict__ partials)
{
    __shared__ float s2s[VQ_K];
    __shared__ int rowinfo[8 * 16];
    __shared__ double wsum[8];

    const int tid  = threadIdx.x;
    const int wid  = tid >> 6;
    const int lane = tid & 63;
    const int l15  = lane & 15;
    const int kg   = lane >> 4;
    const int rowbase = blockIdx.x * 128 + wid * 16;

    s2s[tid] = s2g[tid];                 // 512 threads cover VQ_K
    __syncthreads();

    // A fragments: z rows -> bf16 hi/lo. lane: row=l15, k=kc*32+kg*8+j
    // (same k-map as B fragments, so mapping beliefs cancel in the dot).
    bf16x8 Ah[2], Al[2];
#pragma unroll
    for (int kc = 0; kc < 2; ++kc) {
        const float* zp = z + (size_t)(rowbase + l15) * VQ_D + kc * 32 + kg * 8;
        const f32x4 v0 = *reinterpret_cast<const f32x4*>(zp);
        const f32x4 v1 = *reinterpret_cast<const f32x4*>(zp + 4);
        bf16x8 ah, al;
#pragma unroll
        for (int j = 0; j < 8; ++j) {
            const float fv = (j < 4) ? v0[j] : v1[j - 4];
            const unsigned short h = f2bf(fv);
            ah[j] = (short)h;
            al[j] = (short)f2bf(__fsub_rn(fv, bf2f(h)));
        }
        Ah[kc] = ah; Al[kc] = al;
    }

    float m1[4], m2[4];
    int   i1[4];
#pragma unroll
    for (int j = 0; j < 4; ++j) { m1[j] = 3.4e38f; m2[j] = 3.4e38f; i1[j] = 0; }

    const bf16x8* BH = reinterpret_cast<const bf16x8*>(ebh);
    const bf16x8* BL = reinterpret_cast<const bf16x8*>(ebl);

#pragma unroll 2
    for (int t = 0; t < 32; ++t) {
        const bf16x8 Bh0 = BH[(t * 2 + 0) * 64 + lane];
        const bf16x8 Bl0 = BL[(t * 2 + 0) * 64 + lane];
        const bf16x8 Bh1 = BH[(t * 2 + 1) * 64 + lane];
        const bf16x8 Bl1 = BL[(t * 2 + 1) * 64 + lane];
        f32x4 acc = {0.f, 0.f, 0.f, 0.f};
        acc = __builtin_amdgcn_mfma_f32_16x16x32_bf16(Ah[0], Bh0, acc, 0, 0, 0);
        acc = __builtin_amdgcn_mfma_f32_16x16x32_bf16(Ah[0], Bl0, acc, 0, 0, 0);
        acc = __builtin_amdgcn_mfma_f32_16x16x32_bf16(Al[0], Bh0, acc, 0, 0, 0);
        acc = __builtin_amdgcn_mfma_f32_16x16x32_bf16(Ah[1], Bh1, acc, 0, 0, 0);
        acc = __builtin_amdgcn_mfma_f32_16x16x32_bf16(Ah[1], Bl1, acc, 0, 0, 0);
        acc = __builtin_amdgcn_mfma_f32_16x16x32_bf16(Al[1], Bh1, acc, 0, 0, 0);

        const float s2v = s2s[t * 16 + l15];   // same addr across kg: broadcast
        const int   cid = t * 16 + l15;
#pragma unroll
        for (int j = 0; j < 4; ++j) {          // row = kg*4 + j (m89 layout)
            const float tv  = fmaf(-2.0f, acc[j], s2v);
            const float o1  = m1[j];
            m1[j] = fminf(o1, tv);
            i1[j] = (tv < o1) ? cid : i1[j];
            m2[j] = fminf(m2[j], fmaxf(tv, o1)); // 2nd-best value (ties->gap 0)
        }
    }

    // Pack to order-keys once, merge top-2 across the 16 l15 lanes.
    unsigned long long k1[4], k2[4];
#pragma unroll
    for (int j = 0; j < 4; ++j) {
        k1[j] = (((unsigned long long)ordkey(m1[j])) << 32) | (unsigned)i1[j];
        k2[j] = (((unsigned long long)ordkey(m2[j])) << 32) | 0x1FFull;
    }
#pragma unroll
    for (int m = 1; m <= 8; m <<= 1) {
#pragma unroll
        for (int j = 0; j < 4; ++j) {
            const unsigned long long o1 = __shfl_xor(k1[j], m, 64);
            const unsigned long long o2 = __shfl_xor(k2[j], m, 64);
            const unsigned long long lo_ = (k1[j] < o1) ? k1[j] : o1;
            const unsigned long long hi_ = (k1[j] < o1) ? o1 : k1[j];
            const unsigned long long s2m = (k2[j] < o2) ? k2[j] : o2;
            k1[j] = lo_;
            k2[j] = (hi_ < s2m) ? hi_ : s2m;
        }
    }
    if (l15 == 0) {
#pragma unroll
        for (int j = 0; j < 4; ++j) {
            const float t1 = ordkey_inv((unsigned)(k1[j] >> 32));
            const float t2 = ordkey_inv((unsigned)(k2[j] >> 32));
            const int idx = (int)(k1[j] & 0x1FFull);
            const int flag = (__fsub_rn(t2, t1) <= W_FLAG) ? 1 : 0;
            rowinfo[wid * 16 + kg * 4 + j] = idx | (flag << 16);
        }
    }

    // ---- slow path: exact (R2-numerics) rescan for flagged rows ----
    for (int r = 0; r < 16; ++r) {
        const int info = rowinfo[wid * 16 + r];   // wave-local LDS broadcast
        if (!(info >> 16)) continue;
        const float* zrow = z + (size_t)(rowbase + r) * VQ_D;
        const float s1 = np_sumsq64_g(zrow);      // numpy pairwise, exact
        unsigned long long best = ~0ull;
#pragma unroll
        for (int i = 0; i < 8; ++i) {
            const int c = lane * 8 + i;
            const float* e = emb + (size_t)c * VQ_D;
            float a = 0.f;
#pragma unroll
            for (int d = 0; d < VQ_D; ++d)        // sequential BLAS k-order
                a = fmaf(zrow[d], e[d], a);
            const float tv = __fadd_rn(__fsub_rn(s1, __fmul_rn(2.0f, a)), s2s[c]);
            // tv ~ 64 > 0 always -> raw-bit order fine here (proven R2).
            const unsigned long long key =
                (((unsigned long long)__float_as_uint(tv)) << 32) | (unsigned)c;
            if (key < best) best = key;
        }
#pragma unroll
        for (int m = 1; m <= 32; m <<= 1) {
            const unsigned long long o = __shfl_xor(best, m, 64);
            best = (o < best) ? o : best;
        }
        if (lane == 0) rowinfo[wid * 16 + r] = (int)(best & 0x1FFull);
    }

    // ---- z_q / STE / loss (ops identical to verified R2/R5) ----
    double lsum = 0.0;
    {
        const int r = lane >> 2, seg = lane & 3;
        const int idx = rowinfo[wid * 16 + r] & 0x1FF;
        const float* zp = z + (size_t)(rowbase + r) * VQ_D + seg * 16;
        const float* ep = emb + (size_t)idx * VQ_D + seg * 16;
        float* qp = zq_out + (size_t)(rowbase + r) * VQ_D + seg * 16;
#pragma unroll
        for (int i = 0; i < 4; ++i) {
            const f32x4 zv = *reinterpret_cast<const f32x4*>(zp + i * 4);
            const f32x4 ev = *reinterpret_cast<const f32x4*>(ep + i * 4);
            f32x4 ov;
#pragma unroll
            for (int j = 0; j < 4; ++j) {
                const float d = __fsub_rn(ev[j], zv[j]);
                ov[j] = __fadd_rn(zv[j], d);
                lsum += (double)__fmul_rn(d, d);
            }
            *reinterpret_cast<f32x4*>(qp + i * 4) = ov;
        }
        if (lane < 16)
            idx_out[rowbase + lane] = (float)(rowinfo[wid * 16 + lane] & 0x1FF);
    }

    // ---- deterministic loss reduction ----
#pragma unroll
    for (int off = 32; off > 0; off >>= 1)
        lsum += __shfl_down(lsum, off, 64);
    if (lane == 0) wsum[wid] = lsum;
    __syncthreads();
    if (tid == 0) {
        double s = 0.0;
#pragma unroll
        for (int w = 0; w < 8; ++w) s += wsum[w];
        partials[blockIdx.x] = s;
    }
}

// ---------------------------------------------------------------------------
// Finalize: reduce partials -> loss = 1.25 * sum / N.
// ---------------------------------------------------------------------------
__global__ __launch_bounds__(256) void vq_finalize_kernel(
    const double* __restrict__ partials, int nparts,
    float* __restrict__ loss_out, double inv_n)
{
    __shared__ double ws[4];
    double s = 0.0;
    for (int i = threadIdx.x; i < nparts; i += 256) s += partials[i];
#pragma unroll
    for (int off = 32; off > 0; off >>= 1)
        s += __shfl_down(s, off, 64);
    const int lane = threadIdx.x & 63, w = threadIdx.x >> 6;
    if (lane == 0) ws[w] = s;
    __syncthreads();
    if (threadIdx.x == 0)
        loss_out[0] = (float)(1.25 * (ws[0] + ws[1] + ws[2] + ws[3]) * inv_n);
}

// ---------------------------------------------------------------------------
// Fallback (proven R2 kernel) if ws is too small for the MFMA path.
// ---------------------------------------------------------------------------
__global__ __launch_bounds__(256) void vq_main_kernel(
    const float* __restrict__ z, const float* __restrict__ emb,
    float* __restrict__ zq_out, float* __restrict__ idx_out,
    double* __restrict__ partials, int rows, int use_atomic)
{
    __shared__ float s2[VQ_K];
    __shared__ double wsb[4];
    for (int k = threadIdx.x; k < VQ_K; k += 256)
        s2[k] = np_sumsq64_g(emb + (size_t)k * VQ_D);
    __syncthreads();
    const int row = blockIdx.x * 256 + threadIdx.x;
    double lsum = 0.0;
    if (row < rows) {
        float zr[VQ_D];
        const float* zp = z + (size_t)row * VQ_D;
#pragma unroll
        for (int d = 0; d < VQ_D; d += 4) {
            const float4 v = *reinterpret_cast<const float4*>(zp + d);
            zr[d] = v.x; zr[d+1] = v.y; zr[d+2] = v.z; zr[d+3] = v.w;
        }
        const float s1 = np_sumsq64_g(zr);
        float best = 3.4e38f; int bi = 0;
        for (int k = 0; k < VQ_K; k += 4) {
            const float* e0 = emb + (size_t)(k+0) * VQ_D;
            const float* e1 = emb + (size_t)(k+1) * VQ_D;
            const float* e2 = emb + (size_t)(k+2) * VQ_D;
            const float* e3 = emb + (size_t)(k+3) * VQ_D;
            float a0=0.f,a1=0.f,a2=0.f,a3=0.f;
#pragma unroll
            for (int d = 0; d < VQ_D; ++d) {
                const float zd = zr[d];
                a0 = fmaf(zd, e0[d], a0); a1 = fmaf(zd, e1[d], a1);
                a2 = fmaf(zd, e2[d], a2); a3 = fmaf(zd, e3[d], a3);
            }
            float t;
            t = __fadd_rn(__fsub_rn(s1, __fmul_rn(2.0f, a0)), s2[k+0]);
            if (t < best) { best = t; bi = k+0; }
            t = __fadd_rn(__fsub_rn(s1, __fmul_rn(2.0f, a1)), s2[k+1]);
            if (t < best) { best = t; bi = k+1; }
            t = __fadd_rn(__fsub_rn(s1, __fmul_rn(2.0f, a2)), s2[k+2]);
            if (t < best) { best = t; bi = k+2; }
            t = __fadd_rn(__fsub_rn(s1, __fmul_rn(2.0f, a3)), s2[k+3]);
            if (t < best) { best = t; bi = k+3; }
        }
        const float* eb = emb + (size_t)bi * VQ_D;
        float* zq = zq_out + (size_t)row * VQ_D;
#pragma unroll
        for (int d = 0; d < VQ_D; d += 4) {
            float4 ev, ov;
            ev.x = eb[d]; ev.y = eb[d+1]; ev.z = eb[d+2]; ev.w = eb[d+3];
            const float d0 = __fsub_rn(ev.x, zr[d]);
            const float d1 = __fsub_rn(ev.y, zr[d+1]);
            const float d2 = __fsub_rn(ev.z, zr[d+2]);
            const float d3 = __fsub_rn(ev.w, zr[d+3]);
            ov.x = __fadd_rn(zr[d], d0);   ov.y = __fadd_rn(zr[d+1], d1);
            ov.z = __fadd_rn(zr[d+2], d2); ov.w = __fadd_rn(zr[d+3], d3);
            *reinterpret_cast<float4*>(zq + d) = ov;
            lsum += (double)__fmul_rn(d0,d0) + (double)__fmul_rn(d1,d1)
                  + (double)__fmul_rn(d2,d2) + (double)__fmul_rn(d3,d3);
        }
        idx_out[row] = (float)bi;
    }
#pragma unroll
    for (int off = 32; off > 0; off >>= 1)
        lsum += __shfl_down(lsum, off, 64);
    const int lane = threadIdx.x & 63, w = threadIdx.x >> 6;
    if (lane == 0) wsb[w] = lsum;
    __syncthreads();
    if (threadIdx.x == 0) {
        const double bs = wsb[0] + wsb[1] + wsb[2] + wsb[3];
        if (use_atomic) atomicAdd(partials, bs);
        else partials[blockIdx.x] = bs;
    }
}

extern "C" void kernel_launch(void* const* d_in, const int* in_sizes, int n_in,
                              void* d_out, int out_size, void* d_ws, size_t ws_size,
                              hipStream_t stream) {
    const float* z   = (const float*)d_in[0];
    const float* emb = (const float*)d_in[1];
    float* out = (float*)d_out;

    const int zn   = in_sizes[0];        // 16777216
    const int rows = zn / VQ_D;          // 262144

    float* zq_out   = out;
    float* loss_out = out + zn;
    float* idx_out  = out + zn + 1;

    // ws: [0) ebh 64KB | [64K) ebl 64KB | [128K) s2 2KB | [130K) partials
    const size_t OFF_EBL  = 65536, OFF_S2 = 131072, OFF_PART = 133120;
    const int nblocks = rows / 128;      // 2048
    const size_t need = OFF_PART + (size_t)nblocks * sizeof(double);

    if (ws_size >= need && (rows % 128) == 0) {
        unsigned short* ebh = (unsigned short*)d_ws;
        unsigned short* ebl = (unsigned short*)((char*)d_ws + OFF_EBL);
        float* s2g          = (float*)((char*)d_ws + OFF_S2);
        double* partials    = (double*)((char*)d_ws + OFF_PART);

        vq_prep<<<16, 256, 0, stream>>>(emb, ebh, ebl, s2g);
        vq_mfma_kernel<<<nblocks, 512, 0, stream>>>(
            z, emb, ebh, ebl, s2g, zq_out, idx_out, partials);
        vq_finalize_kernel<<<1, 256, 0, stream>>>(
            partials, nblocks, loss_out, 1.0 / (double)zn);
    } else {
        const int grid = (rows + 255) / 256;
        double* partials = (double*)d_ws;
        const int use_atomic = (ws_size < (size_t)grid * sizeof(double)) ? 1 : 0;
        if (use_atomic) hipMemsetAsync(d_ws, 0, sizeof(double), stream);
        vq_main_kernel<<<grid, 256, 0, stream>>>(z, emb, zq_out, idx_out,
                                                 partials, rows, use_atomic);
        vq_finalize_kernel<<<1, 256, 0, stream>>>(partials, use_atomic ? 1 : grid,
                                                  loss_out, 1.0 / (double)zn);
    }
}